// Round 3
// baseline (276.950 us; speedup 1.0000x reference)
//
#include <hip/hip_runtime.h>
#include <math.h>

#define D 64
#define K 512
#define BLOCK 256

// Bit-level emulation of the harness's numpy fp32 reference:
//   dist[i,k] = fp32( fp32(sx[i] + se[k]) - fp32(2*dot[i,k]) )
// where sx/se are numpy pairwise sums (8-accumulator kernel for n=64) of the
// fp32-rounded elementwise squares, and dot is a sequential single-
// accumulator FMA chain over j=0..63 (OpenBLAS sgemm microkernel order).
// argmin with strict < (first occurrence), matching np.argmin.
//
// The reference's fp32 distances carry ~ulp(64)=7.6e-6 cancellation error
// (dist ~= 64 +- 0.018); an exact argmin mismatches it on ~dozens of rows
// (rounds 1-2 evidence). So we reproduce its rounding, not improve on it.

// numpy pairwise sum of v[j]*v[j], n=64, contraction OFF so each mul and
// each add rounds separately exactly as numpy's scalar kernel does.
__device__ __forceinline__ float np_sumsq64(const float* v) {
#pragma clang fp contract(off)
    float r[8];
#pragma unroll
    for (int m = 0; m < 8; ++m) r[m] = v[m] * v[m];
#pragma unroll
    for (int i = 8; i < 64; i += 8) {
#pragma unroll
        for (int m = 0; m < 8; ++m) r[m] = r[m] + v[i + m] * v[i + m];
    }
    return ((r[0] + r[1]) + (r[2] + r[3])) + ((r[4] + r[5]) + (r[6] + r[7]));
}

__global__ __launch_bounds__(BLOCK) void vq_main(
    const float* __restrict__ x, const float* __restrict__ emb,
    float* __restrict__ q_out, float* __restrict__ idx_out,
    float* __restrict__ block_sums, int* __restrict__ counts, int N)
{
    __shared__ float se_s[K];
    __shared__ int hist[K];
    __shared__ float red[BLOCK / 64];

    const int tid = threadIdx.x;

    // init LDS histogram + numpy-pairwise ||e_k||^2
    for (int k = tid; k < K; k += BLOCK) {
        hist[k] = 0;
        float er[D];
        const float4* e4 = (const float4*)(emb + (size_t)k * D);
#pragma unroll
        for (int j = 0; j < D / 4; ++j) {
            float4 v = e4[j];
            er[4 * j + 0] = v.x; er[4 * j + 1] = v.y;
            er[4 * j + 2] = v.z; er[4 * j + 3] = v.w;
        }
        se_s[k] = np_sumsq64(er);
    }
    __syncthreads();

    const int row = blockIdx.x * BLOCK + tid;
    const bool valid = row < N;

    // load this thread's row into registers
    float xr[D];
    if (valid) {
        const float4* xp = (const float4*)(x + (size_t)row * D);
#pragma unroll
        for (int j = 0; j < D / 4; ++j) {
            float4 v = xp[j];
            xr[4 * j + 0] = v.x; xr[4 * j + 1] = v.y;
            xr[4 * j + 2] = v.z; xr[4 * j + 3] = v.w;
        }
    } else {
#pragma unroll
        for (int j = 0; j < D; ++j) xr[j] = 0.f;
    }

    const float sx = np_sumsq64(xr);  // numpy-pairwise ||x||^2

    // fp32 argmin over emulated reference distances.
    // dot: ONE sequential fmaf chain in j order (BLAS microkernel order).
    // Embedding reads are wave-uniform -> s_load; k-iterations independent
    // so the scheduler interleaves chains across unrolled iterations/waves.
    float bestd = INFINITY;
    int bi = 0;
    const float4* emb4 = (const float4*)emb;
    for (int k = 0; k < K; ++k) {
        float acc = 0.f;
        const float4* ek = emb4 + k * (D / 4);
#pragma unroll
        for (int j = 0; j < D / 4; ++j) {
            float4 e = ek[j];
            acc = fmaf(xr[4 * j + 0], e.x, acc);
            acc = fmaf(xr[4 * j + 1], e.y, acc);
            acc = fmaf(xr[4 * j + 2], e.z, acc);
            acc = fmaf(xr[4 * j + 3], e.w, acc);
        }
        float t1 = sx + se_s[k];        // fp32 round (numpy broadcast add)
        float d  = t1 - 2.0f * acc;     // 2*acc exact; one more fp32 round
        if (d < bestd) { bestd = d; bi = k; }  // strict <: first min wins
    }

    // histogram (LDS atomics), quantized output, per-thread loss partial
    float s = 0.f;
    if (valid) {
        atomicAdd(&hist[bi], 1);
        const float4* ep = (const float4*)(emb + (size_t)bi * D);
        float4* qp = (float4*)(q_out + (size_t)row * D);
#pragma unroll
        for (int j = 0; j < D / 4; ++j) {
            float4 e = ep[j];
            float dx0 = e.x - xr[4 * j + 0];
            float dx1 = e.y - xr[4 * j + 1];
            float dx2 = e.z - xr[4 * j + 2];
            float dx3 = e.w - xr[4 * j + 3];
            s = fmaf(dx0, dx0, s);
            s = fmaf(dx1, dx1, s);
            s = fmaf(dx2, dx2, s);
            s = fmaf(dx3, dx3, s);
            float4 qs;  // straight-through: x + (q - x)
            qs.x = xr[4 * j + 0] + dx0;
            qs.y = xr[4 * j + 1] + dx1;
            qs.z = xr[4 * j + 2] + dx2;
            qs.w = xr[4 * j + 3] + dx3;
            qp[j] = qs;
        }
        idx_out[row] = (float)bi;
    }

    // block-level loss reduction (per-block partial, no global float atomics)
    for (int off = 32; off; off >>= 1) s += __shfl_down(s, off, 64);
    if ((tid & 63) == 0) red[tid >> 6] = s;
    __syncthreads();  // also guarantees hist[] complete
    if (tid == 0) {
        float t = 0.f;
#pragma unroll
        for (int w = 0; w < BLOCK / 64; ++w) t += red[w];
        block_sums[blockIdx.x] = t;
    }
    // flush histogram to global (int atomics, exact)
    for (int k = tid; k < K; k += BLOCK) atomicAdd(&counts[k], hist[k]);
}

__global__ __launch_bounds__(512) void vq_finalize(
    const float* __restrict__ block_sums, int nblocks,
    const int* __restrict__ counts, float* __restrict__ out_loss,
    float* __restrict__ out_perp, float inv_nelem, float inv_rows)
{
    const int tid = threadIdx.x;
    double ls = 0.0;
    for (int i = tid; i < nblocks; i += 512) ls += (double)block_sums[i];
    double ps = 0.0;
    {
        float p = (float)counts[tid] * inv_rows;     // tid < 512 == K
        ps = (double)(p * logf(p + 1e-10f));
    }
    for (int off = 32; off; off >>= 1) {
        ls += __shfl_down(ls, off, 64);
        ps += __shfl_down(ps, off, 64);
    }
    __shared__ double l8[8], p8[8];
    if ((tid & 63) == 0) { l8[tid >> 6] = ls; p8[tid >> 6] = ps; }
    __syncthreads();
    if (tid == 0) {
        double L = 0.0, P = 0.0;
#pragma unroll
        for (int w = 0; w < 8; ++w) { L += l8[w]; P += p8[w]; }
        // loss = q_latent + 0.25*e_latent; forward values identical
        *out_loss = 1.25f * (float)(L * (double)inv_nelem);
        *out_perp = expf((float)(-P));
    }
}

extern "C" void kernel_launch(void* const* d_in, const int* in_sizes, int n_in,
                              void* d_out, int out_size, void* d_ws, size_t ws_size,
                              hipStream_t stream) {
    const float* x   = (const float*)d_in[0];
    const float* emb = (const float*)d_in[1];
    const int N = in_sizes[0] / D;          // 65536 rows
    const int nblocks = (N + BLOCK - 1) / BLOCK;

    float* out      = (float*)d_out;
    float* loss_out = out;                  // [0]
    float* q_out    = out + 1;              // [1 .. N*D]
    float* perp_out = out + 1 + (size_t)N * D;
    float* idx_out  = perp_out + 1;         // [.. + N]

    float* block_sums = (float*)d_ws;
    int*   counts     = (int*)((char*)d_ws + (((size_t)nblocks * 4 + 255) & ~(size_t)255));

    hipMemsetAsync(counts, 0, K * sizeof(int), stream);
    vq_main<<<nblocks, BLOCK, 0, stream>>>(x, emb, q_out, idx_out,
                                           block_sums, counts, N);
    vq_finalize<<<1, 512, 0, stream>>>(block_sums, nblocks, counts,
                                       loss_out, perp_out,
                                       1.0f / (float)((size_t)N * D),
                                       1.0f / (float)N);
}

// Round 4
// 162.150 us; speedup vs baseline: 1.7080x; 1.7080x over previous
//
#include <hip/hip_runtime.h>
#include <math.h>

#define D 64
#define K 512
#define BLOCK 256
#define KSLICE 128              // K / NSLICES
#define NSLICES 4

// Bit-level emulation of the harness's numpy fp32 reference (validated round
// 3 at absmax 0.0):
//   dist[i,k] = fp32( fp32(sx[i] + se[k]) - 2*dot[i,k] )
// sx/se = numpy pairwise sums (8-accumulator kernel, contraction OFF),
// dot = sequential single-accumulator fmaf chain over j=0..63.
// argmin strict-<, first occurrence.
//
// Round-3 bottleneck: 1 thread/row -> 1024 waves -> 1 wave/SIMD (9.9%
// occupancy), VALUBusy 27.7%: dependent-FMA-chain latency + scalar-cache
// misses fully exposed. This version splits K into 4 slices (grid 256x4),
// staging each 32 KB slice in LDS (broadcast ds_read_b128, conflict-free)
// -> 4 blocks/CU, 4 waves/SIMD of TLP. Per-(row,k) arithmetic unchanged.

// numpy pairwise sum of v[j]*v[j], n=64; contraction OFF so each mul and
// add rounds separately, exactly like numpy's scalar kernel.
__device__ __forceinline__ float np_sumsq64(const float* v) {
#pragma clang fp contract(off)
    float r[8];
#pragma unroll
    for (int m = 0; m < 8; ++m) r[m] = v[m] * v[m];
#pragma unroll
    for (int i = 8; i < 64; i += 8) {
#pragma unroll
        for (int m = 0; m < 8; ++m) r[m] = r[m] + v[i + m] * v[i + m];
    }
    return ((r[0] + r[1]) + (r[2] + r[3])) + ((r[4] + r[5]) + (r[6] + r[7]));
}

// Pass 1: each block scans KSLICE codes for BLOCK rows; writes (d, k) into
// the q-region of d_out (stash), later overwritten by vq_merge.
__global__ __launch_bounds__(BLOCK, 4) void vq_scan(
    const float* __restrict__ x, const float* __restrict__ emb,
    float* __restrict__ stash, int N)
{
    __shared__ float4 e_s[KSLICE * (D / 4)];   // 32 KB slice
    __shared__ float se_s[KSLICE];

    const int tid = threadIdx.x;
    const int kbase = blockIdx.y * KSLICE;

    // stage slice into LDS, coalesced: 2048 float4s, 8 per thread
    const float4* esrc = (const float4*)(emb + (size_t)kbase * D);
#pragma unroll
    for (int i = 0; i < (KSLICE * D / 4) / BLOCK; ++i)
        e_s[tid + i * BLOCK] = esrc[tid + i * BLOCK];

    // numpy-pairwise ||e_k||^2 from global (registers; avoids LDS conflicts)
    if (tid < KSLICE) {
        float er[D];
        const float4* e4 = (const float4*)(emb + (size_t)(kbase + tid) * D);
#pragma unroll
        for (int j = 0; j < D / 4; ++j) {
            float4 v = e4[j];
            er[4 * j + 0] = v.x; er[4 * j + 1] = v.y;
            er[4 * j + 2] = v.z; er[4 * j + 3] = v.w;
        }
        se_s[tid] = np_sumsq64(er);
    }
    __syncthreads();

    const int row = blockIdx.x * BLOCK + tid;
    if (row >= N) return;

    float xr[D];
    {
        const float4* xp = (const float4*)(x + (size_t)row * D);
#pragma unroll
        for (int j = 0; j < D / 4; ++j) {
            float4 v = xp[j];
            xr[4 * j + 0] = v.x; xr[4 * j + 1] = v.y;
            xr[4 * j + 2] = v.z; xr[4 * j + 3] = v.w;
        }
    }
    const float sx = np_sumsq64(xr);

    // two interleaved sequential fmaf chains (ILP=2) x 4 waves/SIMD of TLP
    float bestd = INFINITY;
    int bi = 0;
    for (int k = 0; k < KSLICE; k += 2) {
        float a0 = 0.f, a1 = 0.f;
        const float4* e0 = &e_s[k * (D / 4)];
        const float4* e1 = &e_s[(k + 1) * (D / 4)];
#pragma unroll
        for (int j = 0; j < D / 4; ++j) {
            float4 ea = e0[j];                 // broadcast ds_read_b128
            float4 eb = e1[j];
            a0 = fmaf(xr[4 * j + 0], ea.x, a0);
            a1 = fmaf(xr[4 * j + 0], eb.x, a1);
            a0 = fmaf(xr[4 * j + 1], ea.y, a0);
            a1 = fmaf(xr[4 * j + 1], eb.y, a1);
            a0 = fmaf(xr[4 * j + 2], ea.z, a0);
            a1 = fmaf(xr[4 * j + 2], eb.z, a1);
            a0 = fmaf(xr[4 * j + 3], ea.w, a0);
            a1 = fmaf(xr[4 * j + 3], eb.w, a1);
        }
        float d0 = (sx + se_s[k]) - 2.0f * a0;      // same rounding as ref
        float d1 = (sx + se_s[k + 1]) - 2.0f * a1;
        if (d0 < bestd) { bestd = d0; bi = k; }     // k before k+1: first-min
        if (d1 < bestd) { bestd = d1; bi = k + 1; }
    }

    // stash (d, global_k) as float2 at q_out[row*64 + 2*slice] (8B-aligned)
    float2 p; p.x = bestd; p.y = (float)(kbase + bi);
    *(float2*)(stash + (size_t)row * D + 2 * blockIdx.y) = p;
}

// Pass 2: merge 4 slice partials (slice order = k order -> first occurrence),
// gather winning code, write q/idx, loss partials, histogram.
__global__ __launch_bounds__(BLOCK) void vq_merge(
    const float* __restrict__ x, const float* __restrict__ emb,
    float* __restrict__ q_out, float* __restrict__ idx_out,
    float* __restrict__ block_sums, int* __restrict__ counts, int N)
{
    __shared__ int hist[K];
    __shared__ float red[BLOCK / 64];
    const int tid = threadIdx.x;
    for (int k = tid; k < K; k += BLOCK) hist[k] = 0;
    __syncthreads();

    const int row = blockIdx.x * BLOCK + tid;
    float s = 0.f;
    if (row < N) {
        float bestd = INFINITY;
        int bi = 0;
#pragma unroll
        for (int sl = 0; sl < NSLICES; ++sl) {
            float2 p = *(const float2*)(q_out + (size_t)row * D + 2 * sl);
            if (p.x < bestd) { bestd = p.x; bi = (int)p.y; }
        }
        atomicAdd(&hist[bi], 1);

        const float4* xp = (const float4*)(x + (size_t)row * D);
        const float4* ep = (const float4*)(emb + (size_t)bi * D);
        float4* qp = (float4*)(q_out + (size_t)row * D);
#pragma unroll
        for (int j = 0; j < D / 4; ++j) {
            float4 xv = xp[j];
            float4 e  = ep[j];
            float dx0 = e.x - xv.x, dx1 = e.y - xv.y;
            float dx2 = e.z - xv.z, dx3 = e.w - xv.w;
            s = fmaf(dx0, dx0, s);
            s = fmaf(dx1, dx1, s);
            s = fmaf(dx2, dx2, s);
            s = fmaf(dx3, dx3, s);
            float4 qs;  // straight-through: x + (q - x)
            qs.x = xv.x + dx0; qs.y = xv.y + dx1;
            qs.z = xv.z + dx2; qs.w = xv.w + dx3;
            qp[j] = qs;
        }
        idx_out[row] = (float)bi;
    }

    for (int off = 32; off; off >>= 1) s += __shfl_down(s, off, 64);
    if ((tid & 63) == 0) red[tid >> 6] = s;
    __syncthreads();
    if (tid == 0) {
        float t = 0.f;
#pragma unroll
        for (int w = 0; w < BLOCK / 64; ++w) t += red[w];
        block_sums[blockIdx.x] = t;
    }
    for (int k = tid; k < K; k += BLOCK) atomicAdd(&counts[k], hist[k]);
}

__global__ __launch_bounds__(512) void vq_finalize(
    const float* __restrict__ block_sums, int nblocks,
    const int* __restrict__ counts, float* __restrict__ out_loss,
    float* __restrict__ out_perp, float inv_nelem, float inv_rows)
{
    const int tid = threadIdx.x;
    double ls = 0.0;
    for (int i = tid; i < nblocks; i += 512) ls += (double)block_sums[i];
    double ps = 0.0;
    {
        float p = (float)counts[tid] * inv_rows;     // tid < 512 == K
        ps = (double)(p * logf(p + 1e-10f));
    }
    for (int off = 32; off; off >>= 1) {
        ls += __shfl_down(ls, off, 64);
        ps += __shfl_down(ps, off, 64);
    }
    __shared__ double l8[8], p8[8];
    if ((tid & 63) == 0) { l8[tid >> 6] = ls; p8[tid >> 6] = ps; }
    __syncthreads();
    if (tid == 0) {
        double L = 0.0, P = 0.0;
#pragma unroll
        for (int w = 0; w < 8; ++w) { L += l8[w]; P += p8[w]; }
        // loss = q_latent + 0.25*e_latent; forward values identical
        *out_loss = 1.25f * (float)(L * (double)inv_nelem);
        *out_perp = expf((float)(-P));
    }
}

extern "C" void kernel_launch(void* const* d_in, const int* in_sizes, int n_in,
                              void* d_out, int out_size, void* d_ws, size_t ws_size,
                              hipStream_t stream) {
    const float* x   = (const float*)d_in[0];
    const float* emb = (const float*)d_in[1];
    const int N = in_sizes[0] / D;          // 65536 rows
    const int nblocks = (N + BLOCK - 1) / BLOCK;

    float* out      = (float*)d_out;
    float* loss_out = out;                  // [0]
    float* q_out    = out + 1;              // [1 .. N*D]
    float* perp_out = out + 1 + (size_t)N * D;
    float* idx_out  = perp_out + 1;         // [.. + N]

    float* block_sums = (float*)d_ws;
    int*   counts     = (int*)((char*)d_ws + (((size_t)nblocks * 4 + 255) & ~(size_t)255));

    hipMemsetAsync(counts, 0, K * sizeof(int), stream);
    dim3 sgrid(nblocks, NSLICES);
    vq_scan<<<sgrid, BLOCK, 0, stream>>>(x, emb, q_out, N);
    vq_merge<<<nblocks, BLOCK, 0, stream>>>(x, emb, q_out, idx_out,
                                            block_sums, counts, N);
    vq_finalize<<<1, 512, 0, stream>>>(block_sums, nblocks, counts,
                                       loss_out, perp_out,
                                       1.0f / (float)((size_t)N * D),
                                       1.0f / (float)N);
}